// Round 5
// baseline (431.246 us; speedup 1.0000x reference)
//
#include <hip/hip_runtime.h>

#define B_    4096
#define H_    1024
#define NLAY  4

typedef __attribute__((ext_vector_type(8))) short bf16x8;
typedef __attribute__((ext_vector_type(4))) short s16x4;
typedef __attribute__((ext_vector_type(4))) float f32x4;
typedef unsigned short ushort_t;

__device__ __forceinline__ ushort_t f2bf(float f) {
  unsigned u = __builtin_bit_cast(unsigned, f);
  u += 0x7FFFu + ((u >> 16) & 1u);
  return (ushort_t)(u >> 16);
}

__device__ __forceinline__ float fast_sigmoid(float x) {
  float e = __expf(-fabsf(x));
  float s = 1.0f / (1.0f + e);
  return x >= 0.0f ? s : 1.0f - s;
}
__device__ __forceinline__ float fast_tanh(float x) {
  float e = __expf(-2.0f * fabsf(x));
  float t = (1.0f - e) / (1.0f + e);
  return x >= 0.0f ? t : -t;
}

#define GLDS16(gsrc, ldst)                                                  \
  __builtin_amdgcn_global_load_lds(                                         \
      (__attribute__((address_space(1))) void*)(gsrc),                      \
      (__attribute__((address_space(3))) void*)(ldst), 16, 0, 0)

#define BAR()                                                               \
  { asm volatile("" ::: "memory");                                          \
    __builtin_amdgcn_s_barrier();                                           \
    asm volatile("" ::: "memory"); }

#define WAITV(N)                                                            \
  { asm volatile("s_waitcnt vmcnt(" #N ")" ::: "memory");                   \
    __builtin_amdgcn_sched_barrier(0); }

// ---------------------------------------------------------------------------
// LSTM layer, B-in-registers design.
// Block: BM=128 rows x 256 packed gate-cols (4 gates x 64 hcols), 4 waves
// (wave = 128 rows x 16 hcols x 4 gates), BK=32, 64 K-tiles, grid 512.
// A: LDS 4-buffer pipeline (8 KB/buffer, 32 KB total) via global_load_lds,
//    prefetch depth 3.  Buffer row r (128) x 32 k; slot s of row r holds
//    k-octet o = s ^ ((r>>1)&3) (conflict-free ds_read_b128).
// B: NO LDS — weights packed as fragment-ordered 1KB lane-chunks, loaded
//    global->VGPR (coalesced dwordx4) 2 tiles ahead into 4 rotating sets.
// Sync: one {WAITV(8); s_barrier} per tile (counted, never drains mid-loop).
//   Per-tile issue order [B(t+2) x4, A(t+3) x2] -> queue at tile-t end:
//   [A(t+1)2 B(t+1)4 | A(t+2)2 B(t+2)4 A(t+3)2] -> need first 6 -> vmcnt(8).
// 2 blocks/CU resident (32 KB LDS, <=256 VGPR) -> independent barrier
// domains hide each other's stalls.
// ---------------------------------------------------------------------------
__global__ __launch_bounds__(256, 2) void lstm8(
    const ushort_t* __restrict__ aX, const ushort_t* __restrict__ aH,
    const float* __restrict__ cprev, const float* __restrict__ bi,
    const float* __restrict__ bh, const ushort_t* __restrict__ wtl,
    float* __restrict__ hout, float* __restrict__ cout,
    ushort_t* __restrict__ hbfout) {
  __shared__ __align__(16) char sL[32768];

  const int tid  = threadIdx.x;
  const int lane = tid & 63;
  const int wid  = tid >> 6;                  // wave = wn 0..3
  const int bid  = (blockIdx.x & 7) * 64 + (blockIdx.x >> 3);  // XCD-chunked
  const int bm   = bid & 31;
  const int bn   = bid >> 5;

  const int fr = lane & 15;
  const int oF = lane >> 4;
  const int aBase = fr * 64 + (oF ^ ((fr >> 1) & 3)) * 16;

  // A-staging source coords (chunk q = c*256+tid -> lds byte q*16)
  const int rowA = tid >> 2;
  const int oA   = (tid & 3) ^ ((rowA >> 1) & 3);
  const size_t aOff = (size_t)(bm * 128 + rowA) * 1024 + oA * 8;

  const ushort_t* wtBn = wtl + (size_t)bn * 524288;   // 64 tiles * 8192

  f32x4 acc[8][4];
#pragma unroll
  for (int m = 0; m < 8; ++m)
#pragma unroll
    for (int g = 0; g < 4; ++g) acc[m][g] = (f32x4){0.f, 0.f, 0.f, 0.f};

  bf16x8 bs0[4], bs1[4], bs2[4], bs3[4];

#define STAGE_A(NB, T)                                                       \
  {                                                                          \
    const ushort_t* s0 = (((T) < 32) ? aX : aH) + aOff + ((T) & 31) * 32;    \
    GLDS16(s0,         sL + (NB) * 8192 + wid * 1024);                       \
    GLDS16(s0 + 65536, sL + (NB) * 8192 + 4096 + wid * 1024);                \
  }
#define LOADB(SET, T)                                                        \
  {                                                                          \
    const ushort_t* b0 =                                                     \
        wtBn + ((size_t)(T) * 16 + wid * 4) * 512 + lane * 8;                \
    SET[0] = *(const bf16x8*)(b0);                                           \
    SET[1] = *(const bf16x8*)(b0 + 512);                                     \
    SET[2] = *(const bf16x8*)(b0 + 1024);                                    \
    SET[3] = *(const bf16x8*)(b0 + 1536);                                    \
  }

  // prologue: positions [A0 2][B0 4][A1 2][B1 4][A2 2] -> WAITV(8) = A0,B0
  STAGE_A(0, 0)
  LOADB(bs0, 0)
  STAGE_A(1, 1)
  LOADB(bs1, 1)
  STAGE_A(2, 2)
  WAITV(8)
  BAR()

#define TSTEP(CB, NB, T, BU, BL, IB, IA)                                     \
  {                                                                          \
    const char* pa = sL + (CB) * 8192;                                       \
    bf16x8 a[4];                                                             \
    _Pragma("unroll")                                                        \
    for (int m = 0; m < 4; ++m)                                              \
      a[m] = *(const bf16x8*)(pa + aBase + m * 1024);                        \
    if (IB) LOADB(BL, (T) + 2)                                               \
    __builtin_amdgcn_s_setprio(1);                                           \
    _Pragma("unroll")                                                        \
    for (int g = 0; g < 4; ++g)                                              \
      _Pragma("unroll")                                                      \
      for (int m = 0; m < 4; ++m)                                            \
        acc[m][g] = __builtin_amdgcn_mfma_f32_16x16x32_bf16(a[m], BU[g],     \
                                                            acc[m][g], 0, 0, 0); \
    __builtin_amdgcn_s_setprio(0);                                           \
    _Pragma("unroll")                                                        \
    for (int m = 0; m < 4; ++m)                                              \
      a[m] = *(const bf16x8*)(pa + aBase + 4096 + m * 1024);                 \
    if (IA) STAGE_A(NB, (T) + 3)                                             \
    __builtin_amdgcn_s_setprio(1);                                           \
    _Pragma("unroll")                                                        \
    for (int g = 0; g < 4; ++g)                                              \
      _Pragma("unroll")                                                      \
      for (int m = 0; m < 4; ++m)                                            \
        acc[m + 4][g] = __builtin_amdgcn_mfma_f32_16x16x32_bf16(              \
            a[m], BU[g], acc[m + 4][g], 0, 0, 0);                            \
    __builtin_amdgcn_s_setprio(0);                                           \
  }

#pragma unroll 1
  for (int t = 0; t < 60; t += 4) {
    TSTEP(0, 3, t + 0, bs0, bs2, 1, 1) WAITV(8) BAR()
    TSTEP(1, 0, t + 1, bs1, bs3, 1, 1) WAITV(8) BAR()
    TSTEP(2, 1, t + 2, bs2, bs0, 1, 1) WAITV(8) BAR()
    TSTEP(3, 2, t + 3, bs3, bs1, 1, 1) WAITV(8) BAR()
  }
  TSTEP(0, 3, 60, bs0, bs2, 1, 1) WAITV(8) BAR()
  TSTEP(1, 0, 61, bs1, bs3, 1, 0) WAITV(6) BAR()
  TSTEP(2, 1, 62, bs2, bs0, 0, 0) WAITV(0) BAR()
  TSTEP(3, 2, 63, bs3, bs0, 0, 0)
#undef TSTEP
#undef STAGE_A
#undef LOADB

  // ---- epilogue: LSTM cell + coalesced I/O via LDS bounce (overlays sL) ----
  const int hcolL = wid * 16 + fr;             // 0..63
  const int hcol  = bn * 64 + hcolL;
  float bsum[4];
#pragma unroll
  for (int g = 0; g < 4; ++g)
    bsum[g] = bi[g * 1024 + hcol] + bh[g * 1024 + hcol];

  float* LF = (float*)sL;                      // 128 x 64 fp32 = 32 KB
  const int crow = tid >> 4;                   // 0..15
  const int cc4  = (tid & 15) * 4;
  BAR()
  {
    const float* cp0 = cprev + (size_t)(bm * 128) * 1024 + bn * 64;
#pragma unroll
    for (int i = 0; i < 8; ++i) {
      const int row = i * 16 + crow;
      f32x4 v = *(const f32x4*)(cp0 + (size_t)row * 1024 + cc4);
      *(f32x4*)(LF + row * 64 + cc4) = v;
    }
  }
  BAR()
  float cv[8][4], hv[8][4];
#pragma unroll
  for (int m = 0; m < 8; ++m) {
    const int rowb = m * 16 + oF * 4;
#pragma unroll
    for (int r = 0; r < 4; ++r) {
      const float cp = LF[(rowb + r) * 64 + hcolL];
      const float gi = fast_sigmoid(acc[m][0][r] + bsum[0]);
      const float gf = fast_sigmoid(acc[m][1][r] + bsum[1]);
      const float gg = fast_tanh(acc[m][2][r] + bsum[2]);
      const float go = fast_sigmoid(acc[m][3][r] + bsum[3]);
      const float c  = gf * cp + gi * gg;
      cv[m][r] = c;
      hv[m][r] = go * fast_tanh(c);
    }
  }
  BAR()
#pragma unroll
  for (int m = 0; m < 8; ++m) {
    const int rowb = m * 16 + oF * 4;
#pragma unroll
    for (int r = 0; r < 4; ++r) LF[(rowb + r) * 64 + hcolL] = cv[m][r];
  }
  BAR()
  {
    float* co0 = cout + (size_t)(bm * 128) * 1024 + bn * 64;
#pragma unroll
    for (int i = 0; i < 8; ++i) {
      const int row = i * 16 + crow;
      f32x4 v = *(const f32x4*)(LF + row * 64 + cc4);
      *(f32x4*)(co0 + (size_t)row * 1024 + cc4) = v;
    }
  }
  BAR()
#pragma unroll
  for (int m = 0; m < 8; ++m) {
    const int rowb = m * 16 + oF * 4;
#pragma unroll
    for (int r = 0; r < 4; ++r) LF[(rowb + r) * 64 + hcolL] = hv[m][r];
  }
  BAR()
  {
    float* ho0 = hout + (size_t)(bm * 128) * 1024 + bn * 64;
    ushort_t* hb0 = hbfout + (size_t)(bm * 128) * 1024 + bn * 64;
#pragma unroll
    for (int i = 0; i < 8; ++i) {
      const int row = i * 16 + crow;
      f32x4 v = *(const f32x4*)(LF + row * 64 + cc4);
      *(f32x4*)(ho0 + (size_t)row * 1024 + cc4) = v;
      s16x4 hb;
#pragma unroll
      for (int j = 0; j < 4; ++j) hb[j] = (short)f2bf(v[j]);
      *(s16x4*)(hb0 + (size_t)row * 1024 + cc4) = hb;
    }
  }
}

// ---------------------------------------------------------------------------
// Weight pack: per (l, bn, kt) a 16 KB fragment-ordered image:
// chunk idx = (wn*4+g)*64 + lane; image[idx][j] =
//   W[kt*32 + (lane>>4)*8 + j][g*1024 + bn*64 + wn*16 + (lane&15)]
// so a wave's b-frag (wn,g) is one coalesced 1 KB dwordx4 load.
// ---------------------------------------------------------------------------
__global__ __launch_bounds__(512) void packW(const float* __restrict__ Wi,
                                             const float* __restrict__ Wh,
                                             ushort_t* __restrict__ wt) {
  __shared__ ushort_t t16[64 * 256];   // [kl][packed col p = wn*64+g*16+fr]
  const int bn = blockIdx.x;   // 0..15
  const int kb = blockIdx.y;   // 0..31 (64-k chunks = 2 kt)
  const int l  = blockIdx.z;   // 0..3
  const int tid = threadIdx.x;
  const int kq = tid >> 6, cc = tid & 63;
  const int k0 = kb * 64;
  const float* W = (k0 < 1024)
                       ? (Wi + (size_t)l * 1024 * 4096 + (size_t)k0 * 4096)
                       : (Wh + (size_t)l * 1024 * 4096 + (size_t)(k0 - 1024) * 4096);
#pragma unroll
  for (int kk = 0; kk < 8; ++kk) {
    const int kl = kq * 8 + kk;
#pragma unroll
    for (int g = 0; g < 4; ++g) {
      const float v = W[(size_t)kl * 4096 + g * 1024 + bn * 64 + cc];
      const int p = (cc >> 4) * 64 + g * 16 + (cc & 15);
      t16[kl * 256 + p] = f2bf(v);
    }
  }
  __syncthreads();
#pragma unroll
  for (int half = 0; half < 2; ++half) {
    const int kt = kb * 2 + half;
    ushort_t* tile = wt + (((size_t)l * 16 + bn) * 64 + kt) * 8192;
#pragma unroll
    for (int c = 0; c < 2; ++c) {
      const int idx = c * 512 + tid;          // 0..1023
      const int ln  = idx & 63;
      const int p   = (idx >> 6) * 16 + (ln & 15);   // wn*64+g*16+fr packed col
      const int klb = half * 32 + (ln >> 4) * 8;
      bf16x8 ov;
#pragma unroll
      for (int j = 0; j < 8; ++j) ov[j] = (short)t16[(klb + j) * 256 + p];
      *(bf16x8*)(tile + (size_t)idx * 8) = ov;
    }
  }
}

// ---------------------------------------------------------------------------
// FC path (unchanged 2-phase kernel; ~4% of total work)
// ---------------------------------------------------------------------------
__device__ __forceinline__ int swz(int row, int kelem) {
  return ((row * 64 + kelem) * 2) ^ ((row & 7) << 4);
}

__global__ __launch_bounds__(512) void fc_kernel(
    const ushort_t* __restrict__ wtfc, const ushort_t* __restrict__ abf,
    const float* __restrict__ bias, float* __restrict__ y) {
  __shared__ __align__(16) char sA[128 * 64 * 2];
  __shared__ __align__(16) char sB[64 * 64 * 2];
  const int tid  = threadIdx.x;
  const int lane = tid & 63;
  const int wid  = tid >> 6;
  const int wm   = wid >> 2;
  const int wn   = wid & 3;
  const int bid  = (blockIdx.x & 7) * 64 + (blockIdx.x >> 3);
  const int bm   = bid & 31;
  const int bn   = bid >> 5;

  f32x4 acc[4];
#pragma unroll
  for (int m = 0; m < 4; ++m) acc[m] = (f32x4){0.f, 0.f, 0.f, 0.f};

  const int rloc = wid * 8 + (lane >> 3);
  const int jA   = (lane & 7) ^ ((lane >> 3) & 7);
  const ushort_t* aSrc = abf + (size_t)(bm * 128 + rloc) * 1024 + jA * 8;

  for (int ks = 0; ks < 16; ++ks) {
    __syncthreads();
    GLDS16(wtfc + (size_t)(bn * 16 + ks) * 4096 + tid * 8, sB + wid * 1024);
    const int off = ks * 64;
    GLDS16(aSrc + off,             sA + wid * 1024);
    GLDS16(aSrc + off + 64 * 1024, sA + 8192 + wid * 1024);
    __syncthreads();
#pragma unroll
    for (int kk = 0; kk < 64; kk += 32) {
      const int ke = kk + (lane >> 4) * 8;
      bf16x8 a[4];
#pragma unroll
      for (int m = 0; m < 4; ++m)
        a[m] = *(const bf16x8*)(sA + swz(wm * 64 + m * 16 + (lane & 15), ke));
      bf16x8 b = *(const bf16x8*)(sB + swz(wn * 16 + (lane & 15), ke));
#pragma unroll
      for (int m = 0; m < 4; ++m)
        acc[m] = __builtin_amdgcn_mfma_f32_16x16x32_bf16(a[m], b, acc[m], 0, 0, 0);
    }
  }
  const int col = bn * 64 + wn * 16 + (lane & 15);
  const float bb = bias[col];
#pragma unroll
  for (int m = 0; m < 4; ++m) {
    const int row0 = bm * 128 + wm * 64 + m * 16 + ((lane >> 4) << 2);
#pragma unroll
    for (int r = 0; r < 4; ++r)
      y[(size_t)(row0 + r) * 1024 + col] = acc[m][r] + bb;
  }
}

__global__ __launch_bounds__(512) void transposeFc(const float* __restrict__ W,
                                                   ushort_t* __restrict__ wt) {
  const int bn = blockIdx.x;   // 0..15
  const int ks = blockIdx.y;   // 0..15
  const int tid = threadIdx.x;
  const int c  = tid & 63;
  const int ko = (tid >> 6) * 8;
  float v[8];
#pragma unroll
  for (int j = 0; j < 8; ++j)
    v[j] = W[(size_t)(ks * 64 + ko + j) * 1024 + bn * 64 + c];
  bf16x8 o;
#pragma unroll
  for (int j = 0; j < 8; ++j) o[j] = (short)f2bf(v[j]);
  ushort_t* tile = wt + ((size_t)bn * 16 + ks) * 4096;
  *(bf16x8*)((char*)tile + swz(c, ko)) = o;
}

// fp32 -> bf16 bulk convert (8 elements/thread)
__global__ __launch_bounds__(256) void cvt_bf16(const float* __restrict__ s,
                                                ushort_t* __restrict__ d,
                                                int n8) {
  const int i = blockIdx.x * 256 + threadIdx.x;
  if (i >= n8) return;
  const float* p = s + (size_t)i * 8;
  f32x4 a = ((const f32x4*)p)[0];
  f32x4 b = ((const f32x4*)p)[1];
  bf16x8 o;
#pragma unroll
  for (int j = 0; j < 4; ++j) {
    o[j]     = (short)f2bf(a[j]);
    o[4 + j] = (short)f2bf(b[j]);
  }
  *(bf16x8*)(d + (size_t)i * 8) = o;
}

extern "C" void kernel_launch(void* const* d_in, const int* in_sizes, int n_in,
                              void* d_out, int out_size, void* d_ws,
                              size_t ws_size, hipStream_t stream) {
  const float* x     = (const float*)d_in[0];
  const float* hprev = (const float*)d_in[1];
  const float* cprev = (const float*)d_in[2];
  const float* Wi    = (const float*)d_in[3];
  const float* Wh    = (const float*)d_in[4];
  const float* bi    = (const float*)d_in[5];
  const float* bh    = (const float*)d_in[6];
  const float* fcW   = (const float*)d_in[7];
  const float* fcb   = (const float*)d_in[8];

  float* out = (float*)d_out;
  const size_t BH = (size_t)B_ * H_;          // 4194304
  float* y    = out;
  float* hout = out + BH;
  float* cout = out + 5 * BH;

  const size_t WT_ELEMS = (size_t)4 * 16 * 64 * 8192;   // 33554432
  const size_t FC_ELEMS = (size_t)16 * 16 * 4096;       // 1048576
  ushort_t* wt      = (ushort_t*)d_ws;
  ushort_t* fcwt    = wt + WT_ELEMS;
  ushort_t* xbf     = fcwt + FC_ELEMS;
  ushort_t* hprevbf = xbf + BH;
  ushort_t* houtbf  = hprevbf + 4 * BH;

  packW<<<dim3(16, 32, 4), dim3(512), 0, stream>>>(Wi, Wh, wt);
  transposeFc<<<dim3(16, 16), dim3(512), 0, stream>>>(fcW, fcwt);
  cvt_bf16<<<dim3((int)(BH / 8 / 256)), dim3(256), 0, stream>>>(x, xbf,
                                                                (int)(BH / 8));
  cvt_bf16<<<dim3((int)(4 * BH / 8 / 256)), dim3(256), 0, stream>>>(
      hprev, hprevbf, (int)(4 * BH / 8));

  for (int l = 0; l < NLAY; ++l) {
    const ushort_t* aX  = (l == 0) ? xbf : (houtbf + (size_t)(l - 1) * BH);
    const ushort_t* wtl = wt + (size_t)l * 16 * 64 * 8192;
    lstm8<<<dim3(512), dim3(256), 0, stream>>>(
        aX, hprevbf + (size_t)l * BH, cprev + (size_t)l * BH, bi + l * 4096,
        bh + l * 4096, wtl, hout + (size_t)l * BH, cout + (size_t)l * BH,
        houtbf + (size_t)l * BH);
  }
  fc_kernel<<<dim3(512), dim3(512), 0, stream>>>(fcwt, houtbf + 3 * BH, fcb, y);
}

// Round 6
// 384.485 us; speedup vs baseline: 1.1216x; 1.1216x over previous
//
#include <hip/hip_runtime.h>

#define B_    4096
#define H_    1024
#define NLAY  4

typedef __attribute__((ext_vector_type(8))) short bf16x8;
typedef __attribute__((ext_vector_type(4))) short s16x4;
typedef __attribute__((ext_vector_type(4))) float f32x4;
typedef unsigned short ushort_t;

__device__ __forceinline__ ushort_t f2bf(float f) {
  unsigned u = __builtin_bit_cast(unsigned, f);
  u += 0x7FFFu + ((u >> 16) & 1u);
  return (ushort_t)(u >> 16);
}

__device__ __forceinline__ float fast_sigmoid(float x) {
  float e = __expf(-fabsf(x));
  float s = 1.0f / (1.0f + e);
  return x >= 0.0f ? s : 1.0f - s;
}
__device__ __forceinline__ float fast_tanh(float x) {
  float e = __expf(-2.0f * fabsf(x));
  float t = (1.0f - e) / (1.0f + e);
  return x >= 0.0f ? t : -t;
}

#define GLDS16(gsrc, ldst)                                                  \
  __builtin_amdgcn_global_load_lds(                                         \
      (__attribute__((address_space(1))) void*)(gsrc),                      \
      (__attribute__((address_space(3))) void*)(ldst), 16, 0, 0)

#define BAR()                                                               \
  { asm volatile("" ::: "memory");                                          \
    __builtin_amdgcn_s_barrier();                                           \
    asm volatile("" ::: "memory"); }

#define WAITV(N)                                                            \
  { asm volatile("s_waitcnt vmcnt(" #N ")" ::: "memory");                   \
    __builtin_amdgcn_sched_barrier(0); }

// ---------------------------------------------------------------------------
// m201-style 8-phase fused LSTM layer.
// BM=256 rows x BN=256 packed gate-cols (p = wn*64 + g*16 + hc), BK=64,
// 32 K-tiles, 8 waves (2M x 4N), 512 thr, grid 256 (1 block/CU).
// LDS 128 KB: A[par][half] 4x16KB @0, B[par][half] 4x16KB @64K.
// Half image (16 KB) = [kh 2][row 128][slot 4]x16B, slot s of row r holds
// k-octet o = s ^ ((r>>1)&3)  (zero-conflict ds_read_b128, proven R3/R4).
// Iter = 2 K-tiles (T even in par0, T+1 in par1), 8 phases; per phase:
//   {ds_read quadrant frags | stage one half-tile (2 GLDS)} -> bar ->
//   setprio1 -> 16 MFMA (quadrant x K=64) -> setprio0 -> [vmcnt@p4/p8] -> bar
// Stage schedule: p1:A0(T+1) p2:A1(T+1) p3:B0(T+2) p4:B1(T+2)
//                 p5:A0(T+2) p6:A1(T+2) p7:B0(T+3) p8:B1(T+3)
// vmcnt(4)@p4 forces A(T+1),B(T+1); vmcnt(4)@p8 forces A(T+2),B(T+2).
// ---------------------------------------------------------------------------
__global__ __launch_bounds__(512, 1) void lstm8(
    const ushort_t* __restrict__ aX, const ushort_t* __restrict__ aH,
    const float* __restrict__ cprev, const float* __restrict__ bi,
    const float* __restrict__ bh, const ushort_t* __restrict__ wtl,
    float* __restrict__ hout, float* __restrict__ cout,
    ushort_t* __restrict__ hbfout) {
  __shared__ __align__(16) char sL[131072];

  const int tid  = threadIdx.x;
  const int lane = tid & 63;
  const int wid  = tid >> 6;      // 0..7
  const int wm   = wid >> 2;      // 0..1
  const int wn   = wid & 3;       // 0..3
  const int bid  = (blockIdx.x & 7) * 32 + (blockIdx.x >> 3);  // XCD-chunked
  const int bm   = bid & 15;
  const int bn   = bid >> 4;

  const int fr = lane & 15;
  const int oF = lane >> 4;
  const int sw = (oF ^ ((fr >> 1) & 3)) * 16;
  const int aBase = wm * 16384 + fr * 64 + sw;                 // +par*32768+kh*8192+m*1024
  const int bBase = 65536 + (wn >> 1) * 16384 + (wn & 1) * 4096 + fr * 64 + sw;

  // staging source coords
  const int oA = (tid & 3) ^ ((tid >> 3) & 3);
  const size_t aOff0 = (size_t)(bm * 256 + (tid >> 2)) * 1024 + oA * 8;
  const size_t aOff1 = aOff0 + (size_t)128 * 1024;
  const ushort_t* wtBn = wtl + (size_t)bn * 524288;

  f32x4 acc[8][4];
#pragma unroll
  for (int m = 0; m < 8; ++m)
#pragma unroll
    for (int g = 0; g < 4; ++g) acc[m][g] = (f32x4){0.f, 0.f, 0.f, 0.f};

  bf16x8 ar[4][2], br0[2][2], br1[2][2];

#define STAGE_A(PAR, HALF, TT)                                               \
  {                                                                          \
    const ushort_t* s0 =                                                     \
        (((TT) < 16) ? aX : aH) + ((HALF) ? aOff1 : aOff0) + ((TT) & 15) * 64; \
    char* d = sL + (PAR) * 32768 + (HALF) * 16384 + wid * 1024;              \
    GLDS16(s0, d);                                                           \
    GLDS16(s0 + 32, d + 8192);                                               \
  }
#define STAGE_B(PAR, HALF, TT)                                               \
  {                                                                          \
    const ushort_t* s0 =                                                     \
        wtBn + (size_t)((TT) & 31) * 16384 + (HALF) * 8192 + tid * 8;        \
    char* d = sL + 65536 + (PAR) * 32768 + (HALF) * 16384 + wid * 1024;      \
    GLDS16(s0, d);                                                           \
    GLDS16(s0 + 4096, d + 8192);                                             \
  }
#define RD_A(PAR, MH)                                                        \
  _Pragma("unroll") for (int mp = 0; mp < 4; ++mp)                           \
      _Pragma("unroll") for (int kh = 0; kh < 2; ++kh)                       \
      ar[mp][kh] = *(const bf16x8*)(sL + (PAR) * 32768 + kh * 8192 +         \
                                    ((MH) * 4 + mp) * 1024 + aBase);
#define RD_B(PAR, NH, BR)                                                    \
  _Pragma("unroll") for (int gg = 0; gg < 2; ++gg)                           \
      _Pragma("unroll") for (int kh = 0; kh < 2; ++kh)                       \
      BR[gg][kh] = *(const bf16x8*)(sL + (PAR) * 32768 + kh * 8192 +         \
                                    ((NH) * 2 + gg) * 1024 + bBase);
#define MM(MH, NH, BR)                                                       \
  __builtin_amdgcn_s_setprio(1);                                             \
  _Pragma("unroll") for (int gg = 0; gg < 2; ++gg)                           \
      _Pragma("unroll") for (int mp = 0; mp < 4; ++mp)                       \
      _Pragma("unroll") for (int kh = 0; kh < 2; ++kh)                       \
      acc[(MH) * 4 + mp][(NH) * 2 + gg] =                                    \
          __builtin_amdgcn_mfma_f32_16x16x32_bf16(                           \
              ar[mp][kh], BR[gg][kh], acc[(MH) * 4 + mp][(NH) * 2 + gg],     \
              0, 0, 0);                                                      \
  __builtin_amdgcn_s_setprio(0);

  // ---- prologue: A(0),B(0) then B(1); vmcnt(4) leaves B(1) in flight ----
  STAGE_A(0, 0, 0)
  STAGE_A(0, 1, 0)
  STAGE_B(0, 0, 0)
  STAGE_B(0, 1, 0)
  STAGE_B(1, 0, 1)
  STAGE_B(1, 1, 1)
  WAITV(4)
  BAR()

#pragma unroll 1
  for (int t2 = 0; t2 < 32; t2 += 2) {
    // ---- tile T = t2 (par 0) ----
    RD_A(0, 0) RD_B(0, 0, br0)
    STAGE_A(1, 0, t2 + 1)
    BAR()
    MM(0, 0, br0)
    BAR()

    RD_B(0, 1, br1)
    STAGE_A(1, 1, t2 + 1)
    BAR()
    MM(0, 1, br1)
    BAR()

    RD_A(0, 1)
    STAGE_B(0, 0, (t2 + 2))
    BAR()
    MM(1, 0, br0)
    BAR()

    STAGE_B(0, 1, (t2 + 2))
    BAR()
    MM(1, 1, br1)
    WAITV(4)
    BAR()

    // ---- tile T+1 (par 1) ----
    RD_A(1, 0) RD_B(1, 0, br0)
    STAGE_A(0, 0, (t2 + 2))
    BAR()
    MM(0, 0, br0)
    BAR()

    RD_B(1, 1, br1)
    STAGE_A(0, 1, (t2 + 2))
    BAR()
    MM(0, 1, br1)
    BAR()

    RD_A(1, 1)
    STAGE_B(1, 0, (t2 + 3))
    BAR()
    MM(1, 0, br0)
    BAR()

    STAGE_B(1, 1, (t2 + 3))
    BAR()
    MM(1, 1, br1)
    WAITV(4)
    BAR()
  }
#undef STAGE_A
#undef STAGE_B
#undef RD_A
#undef RD_B
#undef MM

  WAITV(0)
  __syncthreads();

  // ---- epilogue: LSTM cell + coalesced I/O via padded LDS bounce ----
  const int hcolL = wn * 16 + fr;              // 0..63
  const int hcol  = bn * 64 + hcolL;
  float bsum[4];
#pragma unroll
  for (int g = 0; g < 4; ++g)
    bsum[g] = bi[g * 1024 + hcol] + bh[g * 1024 + hcol];

#define LSTRIDE 68
  float* LF = (float*)sL;                      // 256 x 68 fp32 = 69.6 KB
  const int crow = tid >> 4;                   // 0..31
  const int cc4  = (tid & 15) * 4;
  {
    const float* cp0 = cprev + (size_t)(bm * 256) * 1024 + bn * 64;
#pragma unroll
    for (int i = 0; i < 8; ++i) {
      const int row = i * 32 + crow;
      f32x4 v = *(const f32x4*)(cp0 + (size_t)row * 1024 + cc4);
      *(f32x4*)(LF + row * LSTRIDE + cc4) = v;
    }
  }
  __syncthreads();
  float cv[8][4], hv[8][4];
#pragma unroll
  for (int m = 0; m < 8; ++m) {
    const int rowb = wm * 128 + m * 16 + oF * 4;
#pragma unroll
    for (int r = 0; r < 4; ++r) {
      const float cp = LF[(rowb + r) * LSTRIDE + hcolL];
      const float gi = fast_sigmoid(acc[m][0][r] + bsum[0]);
      const float gf = fast_sigmoid(acc[m][1][r] + bsum[1]);
      const float gg = fast_tanh(acc[m][2][r] + bsum[2]);
      const float go = fast_sigmoid(acc[m][3][r] + bsum[3]);
      const float c  = gf * cp + gi * gg;
      cv[m][r] = c;
      hv[m][r] = go * fast_tanh(c);
    }
  }
  __syncthreads();
#pragma unroll
  for (int m = 0; m < 8; ++m) {
    const int rowb = wm * 128 + m * 16 + oF * 4;
#pragma unroll
    for (int r = 0; r < 4; ++r) LF[(rowb + r) * LSTRIDE + hcolL] = cv[m][r];
  }
  __syncthreads();
  {
    float* co0 = cout + (size_t)(bm * 256) * 1024 + bn * 64;
#pragma unroll
    for (int i = 0; i < 8; ++i) {
      const int row = i * 32 + crow;
      f32x4 v = *(const f32x4*)(LF + row * LSTRIDE + cc4);
      *(f32x4*)(co0 + (size_t)row * 1024 + cc4) = v;
    }
  }
  __syncthreads();
#pragma unroll
  for (int m = 0; m < 8; ++m) {
    const int rowb = wm * 128 + m * 16 + oF * 4;
#pragma unroll
    for (int r = 0; r < 4; ++r) LF[(rowb + r) * LSTRIDE + hcolL] = hv[m][r];
  }
  __syncthreads();
  {
    float* ho0 = hout + (size_t)(bm * 256) * 1024 + bn * 64;
    ushort_t* hb0 = hbfout + (size_t)(bm * 256) * 1024 + bn * 64;
#pragma unroll
    for (int i = 0; i < 8; ++i) {
      const int row = i * 32 + crow;
      f32x4 v = *(const f32x4*)(LF + row * LSTRIDE + cc4);
      *(f32x4*)(ho0 + (size_t)row * 1024 + cc4) = v;
      s16x4 hb;
#pragma unroll
      for (int j = 0; j < 4; ++j) hb[j] = (short)f2bf(v[j]);
      *(s16x4*)(hb0 + (size_t)row * 1024 + cc4) = hb;
    }
  }
#undef LSTRIDE
}

// ---------------------------------------------------------------------------
// Weight pack: per (l, bn, T, half) a 16 KB image [kh 2][pcol 128][slot 4]x16B
// slot s of pcol r holds octet o = s^((r>>1)&3): k = T*64 + kh*32 + o*8 + j,
// global pcol p = half*128 + r -> gate col ((p>>4)&3)*1024 + bn*64 +
// (p>>6)*16 + (p&15).
// ---------------------------------------------------------------------------
__global__ __launch_bounds__(512) void packW(const float* __restrict__ Wi,
                                             const float* __restrict__ Wh,
                                             ushort_t* __restrict__ wt) {
  __shared__ ushort_t t16[64 * 256];   // [k-local][packed col]
  const int bn = blockIdx.x;   // 0..15
  const int T  = blockIdx.y;   // 0..31
  const int l  = blockIdx.z;   // 0..3
  const int tid = threadIdx.x;
  const int kq = tid >> 6, cc = tid & 63;
  const int k0 = T * 64;
  const float* W = (k0 < 1024)
                       ? (Wi + (size_t)l * 1024 * 4096 + (size_t)k0 * 4096)
                       : (Wh + (size_t)l * 1024 * 4096 + (size_t)(k0 - 1024) * 4096);
#pragma unroll
  for (int kk = 0; kk < 8; ++kk) {
    const int kl = kq * 8 + kk;
#pragma unroll
    for (int g = 0; g < 4; ++g) {
      const float v = W[(size_t)kl * 4096 + g * 1024 + bn * 64 + cc];
      const int p = (cc >> 4) * 64 + g * 16 + (cc & 15);
      t16[kl * 256 + p] = f2bf(v);
    }
  }
  __syncthreads();
#pragma unroll
  for (int half = 0; half < 2; ++half) {
    ushort_t* img =
        wt + (((size_t)l * 16 + bn) * 32 + T) * 16384 + half * 8192;
#pragma unroll
    for (int c = 0; c < 2; ++c) {
      const int idx = c * 512 + tid;          // chunk 0..1023
      const int kh = idx >> 9;
      const int r  = (idx >> 2) & 127;
      const int s  = idx & 3;
      const int o  = s ^ ((r >> 1) & 3);
      const int klb = kh * 32 + o * 8;
      const int pg  = half * 128 + r;
      bf16x8 ov;
#pragma unroll
      for (int j = 0; j < 8; ++j) ov[j] = (short)t16[(klb + j) * 256 + pg];
      *(bf16x8*)(img + (size_t)idx * 8) = ov;
    }
  }
}

// ---------------------------------------------------------------------------
// FC path (2-phase; ~4% of total work)
// ---------------------------------------------------------------------------
__device__ __forceinline__ int swz(int row, int kelem) {
  return ((row * 64 + kelem) * 2) ^ ((row & 7) << 4);
}

__global__ __launch_bounds__(512) void fc_kernel(
    const ushort_t* __restrict__ wtfc, const ushort_t* __restrict__ abf,
    const float* __restrict__ bias, float* __restrict__ y) {
  __shared__ __align__(16) char sA[128 * 64 * 2];
  __shared__ __align__(16) char sB[64 * 64 * 2];
  const int tid  = threadIdx.x;
  const int lane = tid & 63;
  const int wid  = tid >> 6;
  const int wm   = wid >> 2;
  const int wn   = wid & 3;
  const int bid  = (blockIdx.x & 7) * 64 + (blockIdx.x >> 3);
  const int bm   = bid & 31;
  const int bn   = bid >> 5;

  f32x4 acc[4];
#pragma unroll
  for (int m = 0; m < 4; ++m) acc[m] = (f32x4){0.f, 0.f, 0.f, 0.f};

  const int rloc = wid * 8 + (lane >> 3);
  const int jA   = (lane & 7) ^ ((lane >> 3) & 7);
  const ushort_t* aSrc = abf + (size_t)(bm * 128 + rloc) * 1024 + jA * 8;

  for (int ks = 0; ks < 16; ++ks) {
    __syncthreads();
    GLDS16(wtfc + (size_t)(bn * 16 + ks) * 4096 + tid * 8, sB + wid * 1024);
    const int off = ks * 64;
    GLDS16(aSrc + off,             sA + wid * 1024);
    GLDS16(aSrc + off + 64 * 1024, sA + 8192 + wid * 1024);
    __syncthreads();
#pragma unroll
    for (int kk = 0; kk < 64; kk += 32) {
      const int ke = kk + (lane >> 4) * 8;
      bf16x8 a[4];
#pragma unroll
      for (int m = 0; m < 4; ++m)
        a[m] = *(const bf16x8*)(sA + swz(wm * 64 + m * 16 + (lane & 15), ke));
      bf16x8 b = *(const bf16x8*)(sB + swz(wn * 16 + (lane & 15), ke));
#pragma unroll
      for (int m = 0; m < 4; ++m)
        acc[m] = __builtin_amdgcn_mfma_f32_16x16x32_bf16(a[m], b, acc[m], 0, 0, 0);
    }
  }
  const int col = bn * 64 + wn * 16 + (lane & 15);
  const float bb = bias[col];
#pragma unroll
  for (int m = 0; m < 4; ++m) {
    const int row0 = bm * 128 + wm * 64 + m * 16 + ((lane >> 4) << 2);
#pragma unroll
    for (int r = 0; r < 4; ++r)
      y[(size_t)(row0 + r) * 1024 + col] = acc[m][r] + bb;
  }
}

__global__ __launch_bounds__(512) void transposeFc(const float* __restrict__ W,
                                                   ushort_t* __restrict__ wt) {
  const int bn = blockIdx.x;   // 0..15
  const int ks = blockIdx.y;   // 0..15
  const int tid = threadIdx.x;
  const int c  = tid & 63;
  const int ko = (tid >> 6) * 8;
  float v[8];
#pragma unroll
  for (int j = 0; j < 8; ++j)
    v[j] = W[(size_t)(ks * 64 + ko + j) * 1024 + bn * 64 + c];
  bf16x8 o;
#pragma unroll
  for (int j = 0; j < 8; ++j) o[j] = (short)f2bf(v[j]);
  ushort_t* tile = wt + ((size_t)bn * 16 + ks) * 4096;
  *(bf16x8*)((char*)tile + swz(c, ko)) = o;
}

// fp32 -> bf16 bulk convert (8 elements/thread)
__global__ __launch_bounds__(256) void cvt_bf16(const float* __restrict__ s,
                                                ushort_t* __restrict__ d,
                                                int n8) {
  const int i = blockIdx.x * 256 + threadIdx.x;
  if (i >= n8) return;
  const float* p = s + (size_t)i * 8;
  f32x4 a = ((const f32x4*)p)[0];
  f32x4 b = ((const f32x4*)p)[1];
  bf16x8 o;
#pragma unroll
  for (int j = 0; j < 4; ++j) {
    o[j]     = (short)f2bf(a[j]);
    o[4 + j] = (short)f2bf(b[j]);
  }
  *(bf16x8*)(d + (size_t)i * 8) = o;
}

extern "C" void kernel_launch(void* const* d_in, const int* in_sizes, int n_in,
                              void* d_out, int out_size, void* d_ws,
                              size_t ws_size, hipStream_t stream) {
  const float* x     = (const float*)d_in[0];
  const float* hprev = (const float*)d_in[1];
  const float* cprev = (const float*)d_in[2];
  const float* Wi    = (const float*)d_in[3];
  const float* Wh    = (const float*)d_in[4];
  const float* bi    = (const float*)d_in[5];
  const float* bh    = (const float*)d_in[6];
  const float* fcW   = (const float*)d_in[7];
  const float* fcb   = (const float*)d_in[8];

  float* out = (float*)d_out;
  const size_t BH = (size_t)B_ * H_;          // 4194304
  float* y    = out;
  float* hout = out + BH;
  float* cout = out + 5 * BH;

  const size_t WT_ELEMS = (size_t)4 * 16 * 32 * 16384;  // 33554432
  const size_t FC_ELEMS = (size_t)16 * 16 * 4096;       // 1048576
  ushort_t* wt      = (ushort_t*)d_ws;
  ushort_t* fcwt    = wt + WT_ELEMS;
  ushort_t* xbf     = fcwt + FC_ELEMS;
  ushort_t* hprevbf = xbf + BH;
  ushort_t* houtbf  = hprevbf + 4 * BH;

  packW<<<dim3(16, 32, 4), dim3(512), 0, stream>>>(Wi, Wh, wt);
  transposeFc<<<dim3(16, 16), dim3(512), 0, stream>>>(fcW, fcwt);
  cvt_bf16<<<dim3((int)(BH / 8 / 256)), dim3(256), 0, stream>>>(x, xbf,
                                                                (int)(BH / 8));
  cvt_bf16<<<dim3((int)(4 * BH / 8 / 256)), dim3(256), 0, stream>>>(
      hprev, hprevbf, (int)(4 * BH / 8));

  for (int l = 0; l < NLAY; ++l) {
    const ushort_t* aX  = (l == 0) ? xbf : (houtbf + (size_t)(l - 1) * BH);
    const ushort_t* wtl = wt + (size_t)l * 16 * 32 * 16384;
    lstm8<<<dim3(256), dim3(512), 0, stream>>>(
        aX, hprevbf + (size_t)l * BH, cprev + (size_t)l * BH, bi + l * 4096,
        bh + l * 4096, wtl, hout + (size_t)l * BH, cout + (size_t)l * BH,
        houtbf + (size_t)l * BH);
  }
  fc_kernel<<<dim3(512), dim3(512), 0, stream>>>(fcwt, houtbf + 3 * BH, fcb, y);
}

// Round 7
// 384.468 us; speedup vs baseline: 1.1217x; 1.0000x over previous
//
#include <hip/hip_runtime.h>

#define B_    4096
#define H_    1024
#define NLAY  4

typedef __attribute__((ext_vector_type(8))) short bf16x8;
typedef __attribute__((ext_vector_type(4))) short s16x4;
typedef __attribute__((ext_vector_type(4))) float f32x4;
typedef unsigned short ushort_t;

__device__ __forceinline__ ushort_t f2bf(float f) {
  unsigned u = __builtin_bit_cast(unsigned, f);
  u += 0x7FFFu + ((u >> 16) & 1u);
  return (ushort_t)(u >> 16);
}

__device__ __forceinline__ float fast_sigmoid(float x) {
  float e = __expf(-fabsf(x));
  float s = 1.0f / (1.0f + e);
  return x >= 0.0f ? s : 1.0f - s;
}
__device__ __forceinline__ float fast_tanh(float x) {
  float e = __expf(-2.0f * fabsf(x));
  float t = (1.0f - e) / (1.0f + e);
  return x >= 0.0f ? t : -t;
}

#define GLDS16(gsrc, ldst)                                                  \
  __builtin_amdgcn_global_load_lds(                                         \
      (__attribute__((address_space(1))) void*)(gsrc),                      \
      (__attribute__((address_space(3))) void*)(ldst), 16, 0, 0)

#define BAR()                                                               \
  { asm volatile("" ::: "memory");                                          \
    __builtin_amdgcn_s_barrier();                                           \
    asm volatile("" ::: "memory"); }

#define WAITV(N)                                                            \
  { asm volatile("s_waitcnt vmcnt(" #N ")" ::: "memory");                   \
    __builtin_amdgcn_sched_barrier(0); }

// rule #18: inline-asm ds_read + lgkmcnt(0) needs a following sched_barrier(0)
#define LGKM0()                                                             \
  { asm volatile("s_waitcnt lgkmcnt(0)" ::: "memory");                      \
    __builtin_amdgcn_sched_barrier(0); }

// compiler-invisible LDS read: no GLDS-aliasing vmcnt conservatism possible
__device__ __forceinline__ bf16x8 dsr128(unsigned addr, int imm) {
  bf16x8 r;
  asm volatile("ds_read_b128 %0, %1 offset:%c2"
               : "=v"(r)
               : "v"(addr), "i"(imm));
  return r;
}

// ---------------------------------------------------------------------------
// m201-style 8-phase fused LSTM layer (asm ds_read variant).
// BM=256 rows x BN=256 packed gate-cols (p = wn*64 + g*16 + hc), BK=64,
// 32 K-tiles, 8 waves (2M x 4N), 512 thr, grid 256 (1 block/CU).
// LDS 128 KB: A[par][half] 4x16KB @0, B[par][half] 4x16KB @64K.
// Half image (16 KB) = [kh 2][row 128][slot 4]x16B, slot s of row r holds
// k-octet o = s ^ ((r>>1)&3)  (zero-conflict ds_read_b128, verified R3-R6).
// Iter = 2 K-tiles (par0/par1), 8 phases; per phase:
//   {asm ds_read quadrant frags | stage one half-tile (2 GLDS)} -> bar ->
//   lgkmcnt(0)+schedbar -> setprio1 -> 16 MFMA -> setprio0 -> [vmcnt] -> bar
// vmcnt(4) at phases 4 and 8 only (counted, never drains mid-loop).
// ---------------------------------------------------------------------------
__global__ __launch_bounds__(512, 1) void lstm8(
    const ushort_t* __restrict__ aX, const ushort_t* __restrict__ aH,
    const float* __restrict__ cprev, const float* __restrict__ bi,
    const float* __restrict__ bh, const ushort_t* __restrict__ wtl,
    float* __restrict__ hout, float* __restrict__ cout,
    ushort_t* __restrict__ hbfout) {
  __shared__ __align__(16) char sL[131072];

  const int tid  = threadIdx.x;
  const int lane = tid & 63;
  const int wid  = tid >> 6;      // 0..7
  const int wm   = wid >> 2;      // 0..1
  const int wn   = wid & 3;       // 0..3
  const int bid  = (blockIdx.x & 7) * 32 + (blockIdx.x >> 3);  // XCD-chunked
  const int bm   = bid & 15;
  const int bn   = bid >> 4;

  const int fr = lane & 15;
  const int oF = lane >> 4;
  const int sw = (oF ^ ((fr >> 1) & 3)) * 16;

  const unsigned sBase = (unsigned)(size_t)&sL[0];
  const unsigned aAddr = sBase + (unsigned)(wm * 16384 + fr * 64 + sw);
  const unsigned bAddr = sBase + (unsigned)(65536 + (wn >> 1) * 16384 +
                                            (wn & 1) * 4096 + fr * 64 + sw);

  // staging source coords
  const int oA = (tid & 3) ^ ((tid >> 3) & 3);
  const size_t aOff0 = (size_t)(bm * 256 + (tid >> 2)) * 1024 + oA * 8;
  const size_t aOff1 = aOff0 + (size_t)128 * 1024;
  const ushort_t* wtBn = wtl + (size_t)bn * 524288;

  f32x4 acc[8][4];
#pragma unroll
  for (int m = 0; m < 8; ++m)
#pragma unroll
    for (int g = 0; g < 4; ++g) acc[m][g] = (f32x4){0.f, 0.f, 0.f, 0.f};

  bf16x8 ar[4][2], br0[2][2], br1[2][2];

#define STAGE_A(PAR, HALF, TT)                                               \
  {                                                                          \
    const ushort_t* s0 =                                                     \
        (((TT) < 16) ? aX : aH) + ((HALF) ? aOff1 : aOff0) + ((TT) & 15) * 64; \
    char* d = sL + (PAR) * 32768 + (HALF) * 16384 + wid * 1024;              \
    GLDS16(s0, d);                                                           \
    GLDS16(s0 + 32, d + 8192);                                               \
  }
#define STAGE_B(PAR, HALF, TT)                                               \
  {                                                                          \
    const ushort_t* s0 =                                                     \
        wtBn + (size_t)((TT) & 31) * 16384 + (HALF) * 8192 + tid * 8;        \
    char* d = sL + 65536 + (PAR) * 32768 + (HALF) * 16384 + wid * 1024;      \
    GLDS16(s0, d);                                                           \
    GLDS16(s0 + 4096, d + 8192);                                             \
  }
#define RD_A(PAR, MH)                                                        \
  _Pragma("unroll") for (int mp = 0; mp < 4; ++mp)                           \
      _Pragma("unroll") for (int kh = 0; kh < 2; ++kh)                       \
      ar[mp][kh] = dsr128(aAddr, (PAR) * 32768 + kh * 8192 +                 \
                                     ((MH) * 4 + mp) * 1024);
#define RD_B(PAR, NH, BR)                                                    \
  _Pragma("unroll") for (int gg = 0; gg < 2; ++gg)                           \
      _Pragma("unroll") for (int kh = 0; kh < 2; ++kh)                       \
      BR[gg][kh] = dsr128(bAddr, (PAR) * 32768 + kh * 8192 +                 \
                                     ((NH) * 2 + gg) * 1024);
#define MM(MH, NH, BR)                                                       \
  __builtin_amdgcn_s_setprio(1);                                             \
  _Pragma("unroll") for (int gg = 0; gg < 2; ++gg)                           \
      _Pragma("unroll") for (int mp = 0; mp < 4; ++mp)                       \
      _Pragma("unroll") for (int kh = 0; kh < 2; ++kh)                       \
      acc[(MH) * 4 + mp][(NH) * 2 + gg] =                                    \
          __builtin_amdgcn_mfma_f32_16x16x32_bf16(                           \
              ar[mp][kh], BR[gg][kh], acc[(MH) * 4 + mp][(NH) * 2 + gg],     \
              0, 0, 0);                                                      \
  __builtin_amdgcn_s_setprio(0);

  // ---- prologue: A(0),B(0) then B(1); vmcnt(4) leaves B(1) in flight ----
  STAGE_A(0, 0, 0)
  STAGE_A(0, 1, 0)
  STAGE_B(0, 0, 0)
  STAGE_B(0, 1, 0)
  STAGE_B(1, 0, 1)
  STAGE_B(1, 1, 1)
  WAITV(4)
  BAR()

#pragma unroll 1
  for (int t2 = 0; t2 < 32; t2 += 2) {
    // ---- tile T = t2 (par 0) ----
    RD_A(0, 0) RD_B(0, 0, br0)
    STAGE_A(1, 0, t2 + 1)
    BAR()
    LGKM0()
    MM(0, 0, br0)
    BAR()

    RD_B(0, 1, br1)
    STAGE_A(1, 1, t2 + 1)
    BAR()
    LGKM0()
    MM(0, 1, br1)
    BAR()

    RD_A(0, 1)
    STAGE_B(0, 0, (t2 + 2))
    BAR()
    LGKM0()
    MM(1, 0, br0)
    BAR()

    STAGE_B(0, 1, (t2 + 2))
    BAR()
    MM(1, 1, br1)
    WAITV(4)
    BAR()

    // ---- tile T+1 (par 1) ----
    RD_A(1, 0) RD_B(1, 0, br0)
    STAGE_A(0, 0, (t2 + 2))
    BAR()
    LGKM0()
    MM(0, 0, br0)
    BAR()

    RD_B(1, 1, br1)
    STAGE_A(0, 1, (t2 + 2))
    BAR()
    LGKM0()
    MM(0, 1, br1)
    BAR()

    RD_A(1, 1)
    STAGE_B(1, 0, (t2 + 3))
    BAR()
    LGKM0()
    MM(1, 0, br0)
    BAR()

    STAGE_B(1, 1, (t2 + 3))
    BAR()
    MM(1, 1, br1)
    WAITV(4)
    BAR()
  }
#undef STAGE_A
#undef STAGE_B
#undef RD_A
#undef RD_B
#undef MM

  WAITV(0)
  __syncthreads();

  // ---- epilogue: LSTM cell + coalesced I/O via padded LDS bounce ----
  const int hcolL = wn * 16 + fr;              // 0..63
  const int hcol  = bn * 64 + hcolL;
  float bsum[4];
#pragma unroll
  for (int g = 0; g < 4; ++g)
    bsum[g] = bi[g * 1024 + hcol] + bh[g * 1024 + hcol];

#define LSTRIDE 68
  float* LF = (float*)sL;                      // 256 x 68 fp32 = 69.6 KB
  const int crow = tid >> 4;                   // 0..31
  const int cc4  = (tid & 15) * 4;
  {
    const float* cp0 = cprev + (size_t)(bm * 256) * 1024 + bn * 64;
#pragma unroll
    for (int i = 0; i < 8; ++i) {
      const int row = i * 32 + crow;
      f32x4 v = *(const f32x4*)(cp0 + (size_t)row * 1024 + cc4);
      *(f32x4*)(LF + row * LSTRIDE + cc4) = v;
    }
  }
  __syncthreads();
  float cv[8][4], hv[8][4];
#pragma unroll
  for (int m = 0; m < 8; ++m) {
    const int rowb = wm * 128 + m * 16 + oF * 4;
#pragma unroll
    for (int r = 0; r < 4; ++r) {
      const float cp = LF[(rowb + r) * LSTRIDE + hcolL];
      const float gi = fast_sigmoid(acc[m][0][r] + bsum[0]);
      const float gf = fast_sigmoid(acc[m][1][r] + bsum[1]);
      const float gg = fast_tanh(acc[m][2][r] + bsum[2]);
      const float go = fast_sigmoid(acc[m][3][r] + bsum[3]);
      const float c  = gf * cp + gi * gg;
      cv[m][r] = c;
      hv[m][r] = go * fast_tanh(c);
    }
  }
  __syncthreads();
#pragma unroll
  for (int m = 0; m < 8; ++m) {
    const int rowb = wm * 128 + m * 16 + oF * 4;
#pragma unroll
    for (int r = 0; r < 4; ++r) LF[(rowb + r) * LSTRIDE + hcolL] = cv[m][r];
  }
  __syncthreads();
  {
    float* co0 = cout + (size_t)(bm * 256) * 1024 + bn * 64;
#pragma unroll
    for (int i = 0; i < 8; ++i) {
      const int row = i * 32 + crow;
      f32x4 v = *(const f32x4*)(LF + row * LSTRIDE + cc4);
      *(f32x4*)(co0 + (size_t)row * 1024 + cc4) = v;
    }
  }
  __syncthreads();
#pragma unroll
  for (int m = 0; m < 8; ++m) {
    const int rowb = wm * 128 + m * 16 + oF * 4;
#pragma unroll
    for (int r = 0; r < 4; ++r) LF[(rowb + r) * LSTRIDE + hcolL] = hv[m][r];
  }
  __syncthreads();
  {
    float* ho0 = hout + (size_t)(bm * 256) * 1024 + bn * 64;
    ushort_t* hb0 = hbfout + (size_t)(bm * 256) * 1024 + bn * 64;
#pragma unroll
    for (int i = 0; i < 8; ++i) {
      const int row = i * 32 + crow;
      f32x4 v = *(const f32x4*)(LF + row * LSTRIDE + cc4);
      *(f32x4*)(ho0 + (size_t)row * 1024 + cc4) = v;
      s16x4 hb;
#pragma unroll
      for (int j = 0; j < 4; ++j) hb[j] = (short)f2bf(v[j]);
      *(s16x4*)(hb0 + (size_t)row * 1024 + cc4) = hb;
    }
  }
#undef LSTRIDE
}

// ---------------------------------------------------------------------------
// Weight pack: per (l, bn, T, half) a 16 KB image [kh 2][pcol 128][slot 4]x16B
// slot s of pcol r holds octet o = s^((r>>1)&3): k = T*64 + kh*32 + o*8 + j,
// global pcol p = half*128 + r -> gate col ((p>>4)&3)*1024 + bn*64 +
// (p>>6)*16 + (p&15).
// ---------------------------------------------------------------------------
__global__ __launch_bounds__(512) void packW(const float* __restrict__ Wi,
                                             const float* __restrict__ Wh,
                                             ushort_t* __restrict__ wt) {
  __shared__ ushort_t t16[64 * 256];   // [k-local][packed col]
  const int bn = blockIdx.x;   // 0..15
  const int T  = blockIdx.y;   // 0..31
  const int l  = blockIdx.z;   // 0..3
  const int tid = threadIdx.x;
  const int kq = tid >> 6, cc = tid & 63;
  const int k0 = T * 64;
  const float* W = (k0 < 1024)
                       ? (Wi + (size_t)l * 1024 * 4096 + (size_t)k0 * 4096)
                       : (Wh + (size_t)l * 1024 * 4096 + (size_t)(k0 - 1024) * 4096);
#pragma unroll
  for (int kk = 0; kk < 8; ++kk) {
    const int kl = kq * 8 + kk;
#pragma unroll
    for (int g = 0; g < 4; ++g) {
      const float v = W[(size_t)kl * 4096 + g * 1024 + bn * 64 + cc];
      const int p = (cc >> 4) * 64 + g * 16 + (cc & 15);
      t16[kl * 256 + p] = f2bf(v);
    }
  }
  __syncthreads();
#pragma unroll
  for (int half = 0; half < 2; ++half) {
    ushort_t* img =
        wt + (((size_t)l * 16 + bn) * 32 + T) * 16384 + half * 8192;
#pragma unroll
    for (int c = 0; c < 2; ++c) {
      const int idx = c * 512 + tid;          // chunk 0..1023
      const int kh = idx >> 9;
      const int r  = (idx >> 2) & 127;
      const int s  = idx & 3;
      const int o  = s ^ ((r >> 1) & 3);
      const int klb = kh * 32 + o * 8;
      const int pg  = half * 128 + r;
      bf16x8 ov;
#pragma unroll
      for (int j = 0; j < 8; ++j) ov[j] = (short)t16[(klb + j) * 256 + pg];
      *(bf16x8*)(img + (size_t)idx * 8) = ov;
    }
  }
}

// ---------------------------------------------------------------------------
// FC path (2-phase; ~4% of total work)
// ---------------------------------------------------------------------------
__device__ __forceinline__ int swz(int row, int kelem) {
  return ((row * 64 + kelem) * 2) ^ ((row & 7) << 4);
}

__global__ __launch_bounds__(512) void fc_kernel(
    const ushort_t* __restrict__ wtfc, const ushort_t* __restrict__ abf,
    const float* __restrict__ bias, float* __restrict__ y) {
  __shared__ __align__(16) char sA[128 * 64 * 2];
  __shared__ __align__(16) char sB[64 * 64 * 2];
  const int tid  = threadIdx.x;
  const int lane = tid & 63;
  const int wid  = tid >> 6;
  const int wm   = wid >> 2;
  const int wn   = wid & 3;
  const int bid  = (blockIdx.x & 7) * 64 + (blockIdx.x >> 3);
  const int bm   = bid & 31;
  const int bn   = bid >> 5;

  f32x4 acc[4];
#pragma unroll
  for (int m = 0; m < 4; ++m) acc[m] = (f32x4){0.f, 0.f, 0.f, 0.f};

  const int rloc = wid * 8 + (lane >> 3);
  const int jA   = (lane & 7) ^ ((lane >> 3) & 7);
  const ushort_t* aSrc = abf + (size_t)(bm * 128 + rloc) * 1024 + jA * 8;

  for (int ks = 0; ks < 16; ++ks) {
    __syncthreads();
    GLDS16(wtfc + (size_t)(bn * 16 + ks) * 4096 + tid * 8, sB + wid * 1024);
    const int off = ks * 64;
    GLDS16(aSrc + off,             sA + wid * 1024);
    GLDS16(aSrc + off + 64 * 1024, sA + 8192 + wid * 1024);
    __syncthreads();
#pragma unroll
    for (int kk = 0; kk < 64; kk += 32) {
      const int ke = kk + (lane >> 4) * 8;
      bf16x8 a[4];
#pragma unroll
      for (int m = 0; m < 4; ++m)
        a[m] = *(const bf16x8*)(sA + swz(wm * 64 + m * 16 + (lane & 15), ke));
      bf16x8 b = *(const bf16x8*)(sB + swz(wn * 16 + (lane & 15), ke));
#pragma unroll
      for (int m = 0; m < 4; ++m)
        acc[m] = __builtin_amdgcn_mfma_f32_16x16x32_bf16(a[m], b, acc[m], 0, 0, 0);
    }
  }
  const int col = bn * 64 + wn * 16 + (lane & 15);
  const float bb = bias[col];
#pragma unroll
  for (int m = 0; m < 4; ++m) {
    const int row0 = bm * 128 + wm * 64 + m * 16 + ((lane >> 4) << 2);
#pragma unroll
    for (int r = 0; r < 4; ++r)
      y[(size_t)(row0 + r) * 1024 + col] = acc[m][r] + bb;
  }
}

__global__ __launch_bounds__(512) void transposeFc(const float* __restrict__ W,
                                                   ushort_t* __restrict__ wt) {
  const int bn = blockIdx.x;   // 0..15
  const int ks = blockIdx.y;   // 0..15
  const int tid = threadIdx.x;
  const int c  = tid & 63;
  const int ko = (tid >> 6) * 8;
  float v[8];
#pragma unroll
  for (int j = 0; j < 8; ++j)
    v[j] = W[(size_t)(ks * 64 + ko + j) * 1024 + bn * 64 + c];
  bf16x8 o;
#pragma unroll
  for (int j = 0; j < 8; ++j) o[j] = (short)f2bf(v[j]);
  ushort_t* tile = wt + ((size_t)bn * 16 + ks) * 4096;
  *(bf16x8*)((char*)tile + swz(c, ko)) = o;
}

// fp32 -> bf16 bulk convert (8 elements/thread)
__global__ __launch_bounds__(256) void cvt_bf16(const float* __restrict__ s,
                                                ushort_t* __restrict__ d,
                                                int n8) {
  const int i = blockIdx.x * 256 + threadIdx.x;
  if (i >= n8) return;
  const float* p = s + (size_t)i * 8;
  f32x4 a = ((const f32x4*)p)[0];
  f32x4 b = ((const f32x4*)p)[1];
  bf16x8 o;
#pragma unroll
  for (int j = 0; j < 4; ++j) {
    o[j]     = (short)f2bf(a[j]);
    o[4 + j] = (short)f2bf(b[j]);
  }
  *(bf16x8*)(d + (size_t)i * 8) = o;
}

extern "C" void kernel_launch(void* const* d_in, const int* in_sizes, int n_in,
                              void* d_out, int out_size, void* d_ws,
                              size_t ws_size, hipStream_t stream) {
  const float* x     = (const float*)d_in[0];
  const float* hprev = (const float*)d_in[1];
  const float* cprev = (const float*)d_in[2];
  const float* Wi    = (const float*)d_in[3];
  const float* Wh    = (const float*)d_in[4];
  const float* bi    = (const float*)d_in[5];
  const float* bh    = (const float*)d_in[6];
  const float* fcW   = (const float*)d_in[7];
  const float* fcb   = (const float*)d_in[8];

  float* out = (float*)d_out;
  const size_t BH = (size_t)B_ * H_;          // 4194304
  float* y    = out;
  float* hout = out + BH;
  float* cout = out + 5 * BH;

  const size_t WT_ELEMS = (size_t)4 * 16 * 32 * 16384;  // 33554432
  const size_t FC_ELEMS = (size_t)16 * 16 * 4096;       // 1048576
  ushort_t* wt      = (ushort_t*)d_ws;
  ushort_t* fcwt    = wt + WT_ELEMS;
  ushort_t* xbf     = fcwt + FC_ELEMS;
  ushort_t* hprevbf = xbf + BH;
  ushort_t* houtbf  = hprevbf + 4 * BH;

  packW<<<dim3(16, 32, 4), dim3(512), 0, stream>>>(Wi, Wh, wt);
  transposeFc<<<dim3(16, 16), dim3(512), 0, stream>>>(fcW, fcwt);
  cvt_bf16<<<dim3((int)(BH / 8 / 256)), dim3(256), 0, stream>>>(x, xbf,
                                                                (int)(BH / 8));
  cvt_bf16<<<dim3((int)(4 * BH / 8 / 256)), dim3(256), 0, stream>>>(
      hprev, hprevbf, (int)(4 * BH / 8));

  for (int l = 0; l < NLAY; ++l) {
    const ushort_t* aX  = (l == 0) ? xbf : (houtbf + (size_t)(l - 1) * BH);
    const ushort_t* wtl = wt + (size_t)l * 16 * 32 * 16384;
    lstm8<<<dim3(256), dim3(512), 0, stream>>>(
        aX, hprevbf + (size_t)l * BH, cprev + (size_t)l * BH, bi + l * 4096,
        bh + l * 4096, wtl, hout + (size_t)l * BH, cout + (size_t)l * BH,
        houtbf + (size_t)l * BH);
  }
  fc_kernel<<<dim3(512), dim3(512), 0, stream>>>(fcwt, houtbf + 3 * BH, fcb, y);
}